// Round 10
// baseline (920.615 us; speedup 1.0000x reference)
//
#include <hip/hip_runtime.h>
#include <hip/hip_bf16.h>
#include <hip/hip_cooperative_groups.h>
#include <stdint.h>

namespace cg = cooperative_groups;

#define N_NODES 100000
#define N_RELS  8
#define N_EDGES 150000
#define KCOLS   1152   // K = 8*128 relation cols + 128 self-loop cols
#define CAP     64     // per-dst combined bucket capacity (avg deg = 12)

// pre-work section sizes (256-thread work units)
#define EB_BLOCKS   587                      // ceil(N_EDGES/256)
#define EDGE_SECT   (EB_BLOCKS * N_RELS)     // 4696
#define CAST_BLOCKS 6250                     // N_NODES*16/256
#define PREP_BLOCKS 576                      // 128*KCOLS/256
#define TOTAL_PRE   (EDGE_SECT + CAST_BLOCKS + PREP_BLOCKS)   // 11522

typedef short bf16x8 __attribute__((ext_vector_type(8)));
typedef float f32x4  __attribute__((ext_vector_type(4)));
typedef unsigned int u32;

__device__ __forceinline__ unsigned short f2b(float f) {
    union { float f; unsigned u; } v; v.f = f;
    unsigned r = v.u + 0x7FFF + ((v.u >> 16) & 1);   // RNE
    return (unsigned short)(r >> 16);
}

// async global->LDS, 16 B per lane. LDS pointer MUST be wave-uniform:
// HW writes lds_base + lane*16 (m104/m108). Global address is per-lane.
__device__ __forceinline__ void gld16(const void* g, void* lds_uniform) {
    __builtin_amdgcn_global_load_lds(
        (const __attribute__((address_space(1))) u32*)g,
        (__attribute__((address_space(3))) u32*)lds_uniform,
        16, 0, 0);
}

// ---------------------------------------------------------------------------
// Swizzled storage convention (both-sides-or-neither, guide rule #21):
// every 64-short half-chunk of a row is stored with
//     k_stored = (k & ~63) | ((k & 63) ^ ((row & 7) << 3))
// so the GEMM's linear global_load_lds lands pre-swizzled in LDS and
// ds_read_b128 un-swizzles with  byte ^= ((lane&7)<<4).
// ---------------------------------------------------------------------------

// ---- shared section bodies (used by coop kernel and fallback path) --------
__device__ __forceinline__ void pre_unit(
    unsigned b, int tid,
    const float* __restrict__ x, const float* __restrict__ W,
    const float* __restrict__ Wself,
    const int* __restrict__ src, const int* __restrict__ dst,
    unsigned short* __restrict__ xb, unsigned short* __restrict__ BT,
    int* __restrict__ cnt, int* __restrict__ ebuf) {
    if (b < EDGE_SECT) {
        // ---- edge_build: per-edge scatter into per-dst bucket ----
        int r = b / EB_BLOCKS, eb = b - r * EB_BLOCKS;
        int e = eb * 256 + tid;
        if (e < N_EDGES) {
            int s = src[r * N_EDGES + e];
            int d = dst[r * N_EDGES + e];
            int slot = atomicAdd(&cnt[d], 1);
            if (slot < CAP) ebuf[d * CAP + slot] = (r << 17) | s;
        }
    } else if (b < EDGE_SECT + CAST_BLOCKS) {
        // ---- cast_x: f32 -> bf16, 8 elems/thread, swizzled store ----
        int t = (b - EDGE_SECT) * 256 + tid;
        if (t < N_NODES * 16) {
            int row = t >> 4, g = t & 15;
            const float4* p = (const float4*)(x + (size_t)row * 128 + g * 8);
            float4 a = p[0], bb = p[1];
            unsigned short o[8] = { f2b(a.x), f2b(a.y), f2b(a.z), f2b(a.w),
                                    f2b(bb.x), f2b(bb.y), f2b(bb.z), f2b(bb.w) };
            int g2 = (g & 8) | ((g & 7) ^ (row & 7));
            *(int4*)(xb + (size_t)row * 128 + (g2 << 3)) = *(const int4*)o;
        }
    } else {
        // ---- prep_w: BT[n][k] bf16 weight transpose (swizzled store) ----
        int flat = (int)(b - EDGE_SECT - CAST_BLOCKS) * 256 + tid;
        if (flat < 128 * KCOLS) {
            int n = flat / KCOLS, k = flat - n * KCOLS;
            float v;
            if (k < 1024) {
                int r = k >> 7, kk = k & 127;
                v = W[(r << 14) + (kk << 7) + n];
            } else {
                v = Wself[((k - 1024) << 7) + n];
            }
            int ks = (k & ~63) | ((k & 63) ^ ((n & 7) << 3));
            BT[(size_t)n * KCOLS + ks] = f2b(v);
        }
    }
}

// agg body for one dst d (one wave). Relation-sorted flat walk with forced
// scalarization (readfirstlane) — identical arithmetic/order to round 7.
__device__ __forceinline__ void agg_one(
    int d, int lane,
    const unsigned short* __restrict__ xb, const int* __restrict__ ebuf,
    const int* __restrict__ cnt, unsigned short* __restrict__ Agg) {
    d = __builtin_amdgcn_readfirstlane(d);            // wave-uniform hint

    int k = cnt[d]; if (k > CAP) k = CAP;
    k = __builtin_amdgcn_readfirstlane(k);            // wave-uniform hint
    int rec = (lane < k) ? ebuf[d * CAP + lane] : -1;
    int rl = rec >> 17;                    // -1 for idle lanes

    const unsigned int* xw = (const unsigned int*)xb;   // 2 bf16 per u32

    unsigned long long mask[8];
#pragma unroll
    for (int r = 0; r < 8; ++r) mask[r] = __ballot(rl == r);

    // ---- sort records by relation (stable in lane order) ----
    unsigned long long below = (lane == 63) ? 0x7FFFFFFFFFFFFFFFull
                                            : ((1ull << lane) - 1);
    int pre = 0;
    unsigned long long mymask = 0;
#pragma unroll
    for (int r = 0; r < 8; ++r) {
        pre += (rl > r) ? (int)__popcll(mask[r]) : 0;
        mymask = (rl == r) ? mask[r] : mymask;
    }
    int pos = (rl >= 0) ? (pre + (int)__popcll(mymask & below)) : lane;
    int srt = __builtin_amdgcn_ds_permute(pos << 2, rec);   // dst[pos] = rec

    int swu = lane ^ ((d & 7) << 2);                         // u32 col (swizzled)
    unsigned int* aggRow = (unsigned int*)(Agg + (size_t)d * 1024);

    auto store_r = [&](int rconst, float ax, float ay, int dg) {
        float inv = 1.0f / (float)(dg < 1 ? 1 : dg);
        unsigned int pk = (unsigned int)f2b(ax * inv)
                        | ((unsigned int)f2b(ay * inv) << 16);
        aggRow[(rconst << 6) + swu] = pk;
    };
    auto flush = [&](int r, float ax, float ay) {
        switch (r) {                     // scalar selector -> s_cbranch tree
            case 0: store_r(0, ax, ay, (int)__popcll(mask[0])); break;
            case 1: store_r(1, ax, ay, (int)__popcll(mask[1])); break;
            case 2: store_r(2, ax, ay, (int)__popcll(mask[2])); break;
            case 3: store_r(3, ax, ay, (int)__popcll(mask[3])); break;
            case 4: store_r(4, ax, ay, (int)__popcll(mask[4])); break;
            case 5: store_r(5, ax, ay, (int)__popcll(mask[5])); break;
            case 6: store_r(6, ax, ay, (int)__popcll(mask[6])); break;
            default: store_r(7, ax, ay, (int)__popcll(mask[7])); break;
        }
    };

    float axc = 0.f, ayc = 0.f;
    int cur = 0;
    if (k > 0) cur = __builtin_amdgcn_readlane(srt, 0) >> 17;

    for (int i = 0; i < k; i += 4) {
        int rc4[4];
#pragma unroll
        for (int j = 0; j < 4; ++j) {
            int ii = i + j; if (ii > k - 1) ii = k - 1;      // scalar clamp
            rc4[j] = __builtin_amdgcn_readlane(srt, ii);     // SGPR index
        }
        unsigned int y4[4];
#pragma unroll
        for (int j = 0; j < 4; ++j) {
            int s = rc4[j] & 0x1FFFF;                        // scalar
            y4[j] = xw[(size_t)s * 64 + (lane ^ ((s & 7) << 2))];
        }
#pragma unroll
        for (int j = 0; j < 4; ++j) {
            if (i + j < k) {                                  // scalar branch
                int rr = rc4[j] >> 17;                        // scalar
                if (rr != cur) {                              // scalar, rare
                    flush(cur, axc, ayc);
                    axc = 0.f; ayc = 0.f; cur = rr;
                }
                union { unsigned u; float f; } vx, vy;
                vx.u = y4[j] << 16;
                vy.u = y4[j] & 0xFFFF0000u;
                axc += vx.f;
                ayc += vy.f;
            }
        }
    }
    if (k > 0) flush(cur, axc, ayc);

#pragma unroll
    for (int r = 0; r < 8; ++r)
        if (mask[r] == 0) aggRow[(r << 6) + swu] = 0u;
}

// ---------------------------------------------------------------------------
// Cooperative front: {zero cnt} -> sync -> {edge|cast|prep interleaved} ->
// sync -> {agg}. One dispatch replaces memset+fused_pre+agg_x (saves ~2
// launch gaps). No LDS, low VGPR -> 8 blocks/CU co-resident at grid<=2048.
// Work-unit permutation (x7919 mod 11522, bijective) keeps the latency-bound
// edge scatter overlapped with the BW-bound cast throughout phase 1.
// ---------------------------------------------------------------------------
__global__ __launch_bounds__(256, 8) void coop_front(
    const float* __restrict__ x, const float* __restrict__ W,
    const float* __restrict__ Wself,
    const int* __restrict__ src, const int* __restrict__ dst,
    unsigned short* __restrict__ xb, unsigned short* __restrict__ BT,
    int* __restrict__ cnt, int* __restrict__ ebuf,
    unsigned short* __restrict__ Agg) {
    cg::grid_group g = cg::this_grid();

    // phase 0: zero cnt
    for (int i = blockIdx.x * 256 + threadIdx.x; i < N_NODES;
         i += gridDim.x * 256)
        cnt[i] = 0;
    __threadfence();
    g.sync();

    // phase 1: pre-work, permuted interleave
    for (unsigned bu = blockIdx.x; bu < TOTAL_PRE; bu += gridDim.x) {
        unsigned b = (bu * 7919u) % (unsigned)TOTAL_PRE;
        pre_unit(b, threadIdx.x, x, W, Wself, src, dst, xb, BT, cnt, ebuf);
    }
    __threadfence();
    g.sync();

    // phase 2: aggregation, one wave per dst
    int lane = threadIdx.x & 63;
    for (int vb = blockIdx.x; vb < (N_NODES + 3) / 4; vb += gridDim.x) {
        int d = (vb << 2) + (threadIdx.x >> 6);
        if (d < N_NODES) agg_one(d, lane, xb, ebuf, cnt, Agg);
    }
}

// ---- fallback (round-9 verified path) -------------------------------------
__global__ __launch_bounds__(256) void fused_pre(
    const float* __restrict__ x, const float* __restrict__ W,
    const float* __restrict__ Wself,
    const int* __restrict__ src, const int* __restrict__ dst,
    unsigned short* __restrict__ xb, unsigned short* __restrict__ BT,
    int* __restrict__ cnt, int* __restrict__ ebuf) {
    pre_unit(blockIdx.x, threadIdx.x, x, W, Wself, src, dst, xb, BT, cnt, ebuf);
}

__global__ __launch_bounds__(256) void agg_x(
    const unsigned short* __restrict__ xb, const int* __restrict__ ebuf,
    const int* __restrict__ cnt, unsigned short* __restrict__ Agg) {
    int d = (blockIdx.x << 2) + (threadIdx.x >> 6);
    if (d >= N_NODES) return;
    agg_one(d, threadIdx.x & 63, xb, ebuf, cnt, Agg);
}

// ---------------------------------------------------------------------------
// out[N,128] f32 = relu( [Agg | xb][N,1152] @ BT^T + bias )
// 128x128 out tile/block, 4 waves 2x2. K-loop over 18 half-chunks of 64.
// Double-buffered LDS, global_load_lds staging, XOR-swizzled ds_read.
// ---------------------------------------------------------------------------
__global__ __launch_bounds__(256) void gemm_out(
    const unsigned short* __restrict__ Agg, const unsigned short* __restrict__ xb,
    const unsigned short* __restrict__ BT, const float* __restrict__ bias,
    float* __restrict__ out) {
    __shared__ short As[2][128 * 64];
    __shared__ short Bs[2][128 * 64];
    int t = threadIdx.x;
    int rowBase = blockIdx.x * 128;

    int w = t >> 6, lane = t & 63;
    int wr = w >> 1, wc = w & 1;
    int ml = lane & 15, quad = lane >> 4;
    int sa = (lane & 7) << 4;          // read-side un-swizzle (row&7 == lane&7)

    int ri = lane >> 3;                // row within a 1 KB staging instruction
    int cb = (lane & 7) << 4;          // byte within 128-B row

    f32x4 acc[4][4];
#pragma unroll
    for (int i = 0; i < 4; ++i)
#pragma unroll
        for (int j = 0; j < 4; ++j)
            acc[i][j] = (f32x4){0.f, 0.f, 0.f, 0.f};

    auto stage = [&](int buf, int t2) {
        int kc = t2 >> 1, h = t2 & 1;
#pragma unroll
        for (int j = 0; j < 4; ++j) {
            int i = (w << 2) + j;                 // staging inst 0..15 (uniform)
            int row = (i << 3) + ri;              // LDS row 0..127
            int grow = rowBase + row;
            if (grow > N_NODES - 1) grow = N_NODES - 1;   // tail clamp
            const char* ga = (kc < 8)
                ? (const char*)Agg + (size_t)grow * 2048 + (kc << 8) + (h << 7) + cb
                : (const char*)xb  + (size_t)grow * 256  + (h << 7) + cb;
            gld16(ga, (char*)&As[buf][0] + (i << 10));    // uniform LDS base
            const char* gb = (const char*)BT + (size_t)row * 2304 + (t2 << 7) + cb;
            gld16(gb, (char*)&Bs[buf][0] + (i << 10));    // uniform LDS base
        }
    };

    auto compute = [&](int buf) {
#pragma unroll
        for (int kb = 0; kb < 2; ++kb) {
            int off = ((kb << 6) + (quad << 4)) ^ sa;
            bf16x8 a[4], b[4];
#pragma unroll
            for (int i = 0; i < 4; ++i)
                a[i] = *(const bf16x8*)((const char*)&As[buf][0] +
                        (((wr << 6) + (i << 4) + ml) << 7) + off);
#pragma unroll
            for (int j = 0; j < 4; ++j)
                b[j] = *(const bf16x8*)((const char*)&Bs[buf][0] +
                        (((wc << 6) + (j << 4) + ml) << 7) + off);
#pragma unroll
            for (int i = 0; i < 4; ++i)
#pragma unroll
                for (int j = 0; j < 4; ++j)
                    acc[i][j] = __builtin_amdgcn_mfma_f32_16x16x32_bf16(a[i], b[j], acc[i][j], 0, 0, 0);
        }
    };

    stage(0, 0);
    asm volatile("s_waitcnt vmcnt(0)" ::: "memory");
    __syncthreads();
    int cur = 0;
    for (int t2 = 0; t2 < 18; ++t2) {
        if (t2 + 1 < 18) stage(cur ^ 1, t2 + 1);   // prefetch next half-chunk
        compute(cur);
        asm volatile("s_waitcnt vmcnt(0)" ::: "memory");
        __syncthreads();
        cur ^= 1;
    }

    // epilogue: + bias, relu, f32 store
#pragma unroll
    for (int i = 0; i < 4; ++i) {
#pragma unroll
        for (int j = 0; j < 4; ++j) {
            int col = wc * 64 + j * 16 + ml;
            float bv = bias[col];
#pragma unroll
            for (int rr = 0; rr < 4; ++rr) {
                int row = rowBase + wr * 64 + i * 16 + quad * 4 + rr;
                if (row < N_NODES) {
                    float v = acc[i][j][rr] + bv;
                    out[(size_t)row * 128 + col] = fmaxf(v, 0.f);
                }
            }
        }
    }
}

// ---------------------------------------------------------------------------
extern "C" void kernel_launch(void* const* d_in, const int* in_sizes, int n_in,
                              void* d_out, int out_size, void* d_ws, size_t ws_size,
                              hipStream_t stream) {
    const float* x     = (const float*)d_in[0];
    const float* W     = (const float*)d_in[1];
    const float* Wself = (const float*)d_in[2];
    const float* bias  = (const float*)d_in[3];
    const int*   src   = (const int*)d_in[4];
    const int*   dst   = (const int*)d_in[5];
    float* out = (float*)d_out;

    char* ws = (char*)d_ws;
    size_t off = 0;
    unsigned short* Agg = (unsigned short*)(ws + off); off += (size_t)N_NODES * 1024 * 2; // 204.8 MB
    unsigned short* xb  = (unsigned short*)(ws + off); off += (size_t)N_NODES * 128 * 2;  // 25.6 MB
    unsigned short* BT  = (unsigned short*)(ws + off); off += (size_t)128 * KCOLS * 2;    // 0.3 MB
    int* cnt  = (int*)(ws + off); off += (size_t)N_NODES * 4;                             // 0.4 MB
    int* ebuf = (int*)(ws + off); off += (size_t)N_NODES * CAP * 4;                       // 25.6 MB

    // cooperative front: grid clamped to guaranteed co-residency
    int nb = 0;
    hipError_t qerr = hipOccupancyMaxActiveBlocksPerMultiprocessor(
        &nb, coop_front, 256, 0);
    if (qerr != hipSuccess || nb < 1) nb = 1;
    if (nb > 8) nb = 8;
    int cgrid = nb * 256;                 // 256 CUs on MI355X
    if (cgrid > 2048) cgrid = 2048;

    void* args[] = { (void*)&x, (void*)&W, (void*)&Wself, (void*)&src,
                     (void*)&dst, (void*)&xb, (void*)&BT, (void*)&cnt,
                     (void*)&ebuf, (void*)&Agg };
    hipError_t lerr = hipLaunchCooperativeKernel(
        (void*)coop_front, dim3(cgrid), dim3(256), args, 0, stream);

    if (lerr != hipSuccess) {
        // fallback: verified round-9 3-dispatch path
        hipMemsetAsync(cnt, 0, (size_t)N_NODES * 4, stream);
        fused_pre<<<TOTAL_PRE, 256, 0, stream>>>(x, W, Wself, src, dst,
                                                 xb, BT, cnt, ebuf);
        agg_x<<<(N_NODES + 3) / 4, 256, 0, stream>>>(xb, ebuf, cnt, Agg);
    }

    gemm_out<<<(N_NODES + 127) / 128, 256, 0, stream>>>(Agg, xb, BT, bias, out);
}

// Round 11
// 375.071 us; speedup vs baseline: 2.4545x; 2.4545x over previous
//
#include <hip/hip_runtime.h>
#include <hip/hip_bf16.h>
#include <stdint.h>

#define N_NODES 100000
#define N_RELS  8
#define N_EDGES 150000
#define KCOLS   1152   // K = 8*128 relation cols + 128 self-loop cols
#define CAP     64     // per-dst combined bucket capacity (avg deg = 12)

// pre-work section sizes (256-thread work units)
#define EB_UNITS    147                      // ceil(N_EDGES/1024), 4 edges/thread
#define EDGE_SECT   (EB_UNITS * N_RELS)      // 1176
#define CAST_BLOCKS 6250                     // N_NODES*16/256
#define PREP_BLOCKS 576                      // 128*KCOLS/256
#define TOTAL_PRE   (EDGE_SECT + CAST_BLOCKS + PREP_BLOCKS)   // 8002

typedef short bf16x8 __attribute__((ext_vector_type(8)));
typedef float f32x4  __attribute__((ext_vector_type(4)));
typedef unsigned int u32;

__device__ __forceinline__ unsigned short f2b(float f) {
    union { float f; unsigned u; } v; v.f = f;
    unsigned r = v.u + 0x7FFF + ((v.u >> 16) & 1);   // RNE
    return (unsigned short)(r >> 16);
}

// async global->LDS, 16 B per lane. LDS pointer MUST be wave-uniform:
// HW writes lds_base + lane*16 (m104/m108). Global address is per-lane.
__device__ __forceinline__ void gld16(const void* g, void* lds_uniform) {
    __builtin_amdgcn_global_load_lds(
        (const __attribute__((address_space(1))) u32*)g,
        (__attribute__((address_space(3))) u32*)lds_uniform,
        16, 0, 0);
}

// ---------------------------------------------------------------------------
// Swizzled storage convention (A-side only; both-sides-or-neither, rule #21):
// Agg and xb store every 64-short half-chunk of a row with
//     k_stored = (k & ~63) | ((k & 63) ^ ((row & 7) << 3))
// so the GEMM's linear global_load_lds lands pre-swizzled in LDS and
// ds_read_b128 un-swizzles with  byte ^= ((lane&7)<<4)  (8 lanes per 16-B
// slot = the ds_read_b128 conflict-free optimum). BT is stored LINEAR:
// the GEMM reads B fragments directly from L2 (0.3 MB, resident), no LDS.
// ---------------------------------------------------------------------------

// ---------------------------------------------------------------------------
// Fused prologue: three independent producers in one launch, partitioned by
// blockIdx. edge units FIRST (latency-bound long pole) so cast_x/prep_w
// overlap underneath. Edge units process 4 edges/thread with the 4
// atomicAdds issued back-to-back -> 4 atomic return-latencies in flight
// (was 1/thread = fully exposed).
//   [0, EDGE_SECT)                    edge scatter (1024 edges/unit)
//   [EDGE_SECT, +CAST_BLOCKS)         cast_x: x f32 -> xb bf16 (swizzled)
//   [EDGE_SECT+CAST_BLOCKS, +PREP)    prep_w: W -> BT bf16 transpose (linear)
// ---------------------------------------------------------------------------
__global__ __launch_bounds__(256) void fused_pre(
    const float* __restrict__ x, const float* __restrict__ W,
    const float* __restrict__ Wself,
    const int* __restrict__ src, const int* __restrict__ dst,
    unsigned short* __restrict__ xb, unsigned short* __restrict__ BT,
    int* __restrict__ cnt, int* __restrict__ ebuf) {
    int b = blockIdx.x;
    int tid = threadIdx.x;
    if (b < EDGE_SECT) {
        // ---- edge scatter, 4 edges/thread, batched atomics ----
        int r = b / EB_UNITS, eb = b - r * EB_UNITS;
        int e0 = eb * 1024 + tid;
        const int* sp = src + r * N_EDGES;
        const int* dp = dst + r * N_EDGES;
        int ss[4], dd[4], slot[4];
#pragma unroll
        for (int j = 0; j < 4; ++j) {
            int e = e0 + j * 256;
            if (e < N_EDGES) { ss[j] = sp[e]; dd[j] = dp[e]; }
            else dd[j] = -1;
        }
#pragma unroll
        for (int j = 0; j < 4; ++j)
            if (dd[j] >= 0) slot[j] = atomicAdd(&cnt[dd[j]], 1);
#pragma unroll
        for (int j = 0; j < 4; ++j)
            if (dd[j] >= 0 && slot[j] < CAP)
                ebuf[dd[j] * CAP + slot[j]] = (r << 17) | ss[j];
    } else if (b < EDGE_SECT + CAST_BLOCKS) {
        // ---- cast_x: f32 -> bf16, 8 elems/thread, swizzled store ----
        int t = (b - EDGE_SECT) * 256 + tid;
        if (t < N_NODES * 16) {
            int row = t >> 4, g = t & 15;
            const float4* p = (const float4*)(x + (size_t)row * 128 + g * 8);
            float4 a = p[0], bb = p[1];
            unsigned short o[8] = { f2b(a.x), f2b(a.y), f2b(a.z), f2b(a.w),
                                    f2b(bb.x), f2b(bb.y), f2b(bb.z), f2b(bb.w) };
            int g2 = (g & 8) | ((g & 7) ^ (row & 7));
            *(int4*)(xb + (size_t)row * 128 + (g2 << 3)) = *(const int4*)o;
        }
    } else {
        // ---- prep_w: BT[n][k] bf16 weight transpose (LINEAR store) ----
        int flat = (b - EDGE_SECT - CAST_BLOCKS) * 256 + tid;
        if (flat < 128 * KCOLS) {
            int n = flat / KCOLS, k = flat - n * KCOLS;
            float v;
            if (k < 1024) {
                int r = k >> 7, kk = k & 127;
                v = W[(r << 14) + (kk << 7) + n];
            } else {
                v = Wself[((k - 1024) << 7) + n];
            }
            BT[flat] = f2b(v);
        }
    }
}

// ---------------------------------------------------------------------------
// One wave per dst: Agg[d, r*128:+128] = inv_deg_r * sum_{edges r->d} xb[src]
// Relation-sorted flat walk, forced scalarization (readfirstlane on k,d ->
// all control flow is s_cmp/s_cbranch, readlane indices in SGPRs), 8-deep
// batched gather stream. Accumulation order = stable lane-order sort.
// ---------------------------------------------------------------------------
__global__ __launch_bounds__(256) void agg_x(
    const unsigned short* __restrict__ xb, const int* __restrict__ ebuf,
    const int* __restrict__ cnt, unsigned short* __restrict__ Agg) {
    int d = (blockIdx.x << 2) + (threadIdx.x >> 6);
    if (d >= N_NODES) return;
    d = __builtin_amdgcn_readfirstlane(d);            // wave-uniform hint
    int lane = threadIdx.x & 63;

    int k = cnt[d]; if (k > CAP) k = CAP;
    k = __builtin_amdgcn_readfirstlane(k);            // wave-uniform hint
    int rec = (lane < k) ? ebuf[d * CAP + lane] : -1;
    int rl = rec >> 17;                    // -1 for idle lanes

    const unsigned int* xw = (const unsigned int*)xb;   // 2 bf16 per u32

    unsigned long long mask[8];
#pragma unroll
    for (int r = 0; r < 8; ++r) mask[r] = __ballot(rl == r);

    // ---- sort records by relation (stable in lane order) ----
    unsigned long long below = (lane == 63) ? 0x7FFFFFFFFFFFFFFFull
                                            : ((1ull << lane) - 1);
    int pre = 0;
    unsigned long long mymask = 0;
#pragma unroll
    for (int r = 0; r < 8; ++r) {
        pre += (rl > r) ? (int)__popcll(mask[r]) : 0;
        mymask = (rl == r) ? mask[r] : mymask;
    }
    int pos = (rl >= 0) ? (pre + (int)__popcll(mymask & below)) : lane;
    int srt = __builtin_amdgcn_ds_permute(pos << 2, rec);   // dst[pos] = rec

    int swu = lane ^ ((d & 7) << 2);                         // u32 col (swizzled)
    unsigned int* aggRow = (unsigned int*)(Agg + (size_t)d * 1024);

    auto store_r = [&](int rconst, float ax, float ay, int dg) {
        float inv = 1.0f / (float)(dg < 1 ? 1 : dg);
        unsigned int pk = (unsigned int)f2b(ax * inv)
                        | ((unsigned int)f2b(ay * inv) << 16);
        aggRow[(rconst << 6) + swu] = pk;
    };
    auto flush = [&](int r, float ax, float ay) {
        switch (r) {                     // scalar selector -> s_cbranch tree
            case 0: store_r(0, ax, ay, (int)__popcll(mask[0])); break;
            case 1: store_r(1, ax, ay, (int)__popcll(mask[1])); break;
            case 2: store_r(2, ax, ay, (int)__popcll(mask[2])); break;
            case 3: store_r(3, ax, ay, (int)__popcll(mask[3])); break;
            case 4: store_r(4, ax, ay, (int)__popcll(mask[4])); break;
            case 5: store_r(5, ax, ay, (int)__popcll(mask[5])); break;
            case 6: store_r(6, ax, ay, (int)__popcll(mask[6])); break;
            default: store_r(7, ax, ay, (int)__popcll(mask[7])); break;
        }
    };

    // ---- sorted walk: 8-deep batched loads, scalar boundary flush ----
    float axc = 0.f, ayc = 0.f;
    int cur = 0;
    if (k > 0) cur = __builtin_amdgcn_readlane(srt, 0) >> 17;

    for (int i = 0; i < k; i += 8) {
        int rc8[8];
#pragma unroll
        for (int j = 0; j < 8; ++j) {
            int ii = i + j; if (ii > k - 1) ii = k - 1;      // scalar clamp
            rc8[j] = __builtin_amdgcn_readlane(srt, ii);     // SGPR index
        }
        unsigned int y8[8];
#pragma unroll
        for (int j = 0; j < 8; ++j) {
            int s = rc8[j] & 0x1FFFF;                        // scalar
            y8[j] = xw[(size_t)s * 64 + (lane ^ ((s & 7) << 2))];
        }
#pragma unroll
        for (int j = 0; j < 8; ++j) {
            if (i + j < k) {                                  // scalar branch
                int rr = rc8[j] >> 17;                        // scalar
                if (rr != cur) {                              // scalar, rare
                    flush(cur, axc, ayc);
                    axc = 0.f; ayc = 0.f; cur = rr;
                }
                union { unsigned u; float f; } vx, vy;
                vx.u = y8[j] << 16;
                vy.u = y8[j] & 0xFFFF0000u;
                axc += vx.f;
                ayc += vy.f;
            }
        }
    }
    if (k > 0) flush(cur, axc, ayc);

    // zero-fill relations with no edges (mean = 0)
#pragma unroll
    for (int r = 0; r < 8; ++r)
        if (mask[r] == 0) aggRow[(r << 6) + swu] = 0u;
}

// ---------------------------------------------------------------------------
// out[N,128] f32 = relu( [Agg | xb][N,1152] @ BT^T + bias )
// 128x128 out tile/block, 4 waves 2x2. K-loop over 18 half-chunks of 64.
// A: double-buffered LDS via global_load_lds (XOR-swizzled read, 32 KB).
// B: direct register fragments from global (BT linear, 0.3 MB, L2-resident)
//    -> no B stage, half the LDS, 4 blocks/CU instead of 2.
// ---------------------------------------------------------------------------
__global__ __launch_bounds__(256, 4) void gemm_out(
    const unsigned short* __restrict__ Agg, const unsigned short* __restrict__ xb,
    const unsigned short* __restrict__ BT, const float* __restrict__ bias,
    float* __restrict__ out) {
    __shared__ short As[2][128 * 64];
    int t = threadIdx.x;
    int rowBase = blockIdx.x * 128;

    int w = t >> 6, lane = t & 63;
    int wr = w >> 1, wc = w & 1;
    int ml = lane & 15, quad = lane >> 4;
    int sa = (lane & 7) << 4;          // read-side un-swizzle (row&7 == lane&7)

    int ri = lane >> 3;                // row within a 1 KB staging instruction
    int cb = (lane & 7) << 4;          // byte within 128-B row

    f32x4 acc[4][4];
#pragma unroll
    for (int i = 0; i < 4; ++i)
#pragma unroll
        for (int j = 0; j < 4; ++j)
            acc[i][j] = (f32x4){0.f, 0.f, 0.f, 0.f};

    auto stage = [&](int buf, int t2) {
        int kc = t2 >> 1, h = t2 & 1;
#pragma unroll
        for (int j = 0; j < 4; ++j) {
            int i = (w << 2) + j;                 // staging inst 0..15 (uniform)
            int row = (i << 3) + ri;              // LDS row 0..127
            int grow = rowBase + row;
            if (grow > N_NODES - 1) grow = N_NODES - 1;   // tail clamp
            const char* ga = (kc < 8)
                ? (const char*)Agg + (size_t)grow * 2048 + (kc << 8) + (h << 7) + cb
                : (const char*)xb  + (size_t)grow * 256  + (h << 7) + cb;
            gld16(ga, (char*)&As[buf][0] + (i << 10));    // uniform LDS base
        }
    };

    auto compute = [&](int buf, int t2) {
#pragma unroll
        for (int kb = 0; kb < 2; ++kb) {
            int off = ((kb << 6) + (quad << 4)) ^ sa;
            bf16x8 a[4], b[4];
#pragma unroll
            for (int i = 0; i < 4; ++i)
                a[i] = *(const bf16x8*)((const char*)&As[buf][0] +
                        (((wr << 6) + (i << 4) + ml) << 7) + off);
#pragma unroll
            for (int j = 0; j < 4; ++j) {
                int n = (wc << 6) + (j << 4) + ml;
                b[j] = *(const bf16x8*)&BT[(size_t)n * KCOLS +
                        (t2 << 6) + (kb << 5) + (quad << 3)];
            }
#pragma unroll
            for (int i = 0; i < 4; ++i)
#pragma unroll
                for (int j = 0; j < 4; ++j)
                    acc[i][j] = __builtin_amdgcn_mfma_f32_16x16x32_bf16(a[i], b[j], acc[i][j], 0, 0, 0);
        }
    };

    stage(0, 0);
    asm volatile("s_waitcnt vmcnt(0)" ::: "memory");
    __syncthreads();
    int cur = 0;
    for (int t2 = 0; t2 < 18; ++t2) {
        if (t2 + 1 < 18) stage(cur ^ 1, t2 + 1);   // prefetch next half-chunk
        compute(cur, t2);
        asm volatile("s_waitcnt vmcnt(0)" ::: "memory");
        __syncthreads();
        cur ^= 1;
    }

    // epilogue: + bias, relu, f32 store
#pragma unroll
    for (int i = 0; i < 4; ++i) {
#pragma unroll
        for (int j = 0; j < 4; ++j) {
            int col = wc * 64 + j * 16 + ml;
            float bv = bias[col];
#pragma unroll
            for (int rr = 0; rr < 4; ++rr) {
                int row = rowBase + wr * 64 + i * 16 + quad * 4 + rr;
                if (row < N_NODES) {
                    float v = acc[i][j][rr] + bv;
                    out[(size_t)row * 128 + col] = fmaxf(v, 0.f);
                }
            }
        }
    }
}

// ---------------------------------------------------------------------------
extern "C" void kernel_launch(void* const* d_in, const int* in_sizes, int n_in,
                              void* d_out, int out_size, void* d_ws, size_t ws_size,
                              hipStream_t stream) {
    const float* x     = (const float*)d_in[0];
    const float* W     = (const float*)d_in[1];
    const float* Wself = (const float*)d_in[2];
    const float* bias  = (const float*)d_in[3];
    const int*   src   = (const int*)d_in[4];
    const int*   dst   = (const int*)d_in[5];
    float* out = (float*)d_out;

    char* ws = (char*)d_ws;
    size_t off = 0;
    unsigned short* Agg = (unsigned short*)(ws + off); off += (size_t)N_NODES * 1024 * 2; // 204.8 MB
    unsigned short* xb  = (unsigned short*)(ws + off); off += (size_t)N_NODES * 128 * 2;  // 25.6 MB
    unsigned short* BT  = (unsigned short*)(ws + off); off += (size_t)128 * KCOLS * 2;    // 0.3 MB
    int* cnt  = (int*)(ws + off); off += (size_t)N_NODES * 4;                             // 0.4 MB
    int* ebuf = (int*)(ws + off); off += (size_t)N_NODES * CAP * 4;                       // 25.6 MB

    hipMemsetAsync(cnt, 0, (size_t)N_NODES * 4, stream);

    fused_pre<<<TOTAL_PRE, 256, 0, stream>>>(x, W, Wself, src, dst,
                                             xb, BT, cnt, ebuf);

    agg_x<<<(N_NODES + 3) / 4, 256, 0, stream>>>(xb, ebuf, cnt, Agg);

    gemm_out<<<(N_NODES + 127) / 128, 256, 0, stream>>>(Agg, xb, BT, bias, out);
}

// Round 12
// 318.232 us; speedup vs baseline: 2.8929x; 1.1786x over previous
//
#include <hip/hip_runtime.h>
#include <hip/hip_bf16.h>
#include <stdint.h>

#define N_NODES 100000
#define N_RELS  8
#define N_EDGES 150000
#define KCOLS   1152   // K = 8*128 relation cols + 128 self-loop cols
#define CAP     64     // per-dst combined bucket capacity (avg deg = 12)

// pre-work section sizes (256-thread work units)
#define EB_BLOCKS   587                      // ceil(N_EDGES/256), 1 edge/thread
#define EDGE_SECT   (EB_BLOCKS * N_RELS)     // 4696
#define CAST_BLOCKS 6250                     // N_NODES*16/256
#define PREP_BLOCKS 576                      // 128*KCOLS/256
#define TOTAL_PRE   (EDGE_SECT + CAST_BLOCKS + PREP_BLOCKS)   // 11522

typedef short bf16x8 __attribute__((ext_vector_type(8)));
typedef float f32x4  __attribute__((ext_vector_type(4)));
typedef unsigned int u32;

__device__ __forceinline__ unsigned short f2b(float f) {
    union { float f; unsigned u; } v; v.f = f;
    unsigned r = v.u + 0x7FFF + ((v.u >> 16) & 1);   // RNE
    return (unsigned short)(r >> 16);
}

// async global->LDS, 16 B per lane. LDS pointer MUST be wave-uniform:
// HW writes lds_base + lane*16 (m104/m108). Global address is per-lane.
__device__ __forceinline__ void gld16(const void* g, void* lds_uniform) {
    __builtin_amdgcn_global_load_lds(
        (const __attribute__((address_space(1))) u32*)g,
        (__attribute__((address_space(3))) u32*)lds_uniform,
        16, 0, 0);
}

// ---------------------------------------------------------------------------
// A-side swizzle (both-sides-or-neither, rule #21): Agg and xb store every
// 64-short half-chunk of a row with
//     k_stored = (k & ~63) | ((k & 63) ^ ((row & 7) << 3))
// so the GEMM's linear global_load_lds lands pre-swizzled in LDS and
// ds_read_b128 un-swizzles with  byte ^= ((lane&7)<<4).
//
// B-side: BT2 is stored in MFMA FRAGMENT ORDER —
//     BT2[t2][kb][wc][j][lane][8 shorts],  lane = quad*16 + ml
//     covering k = t2*64 + kb*32 + quad*8 + e,  n = wc*64 + j*16 + ml
// so each b[j] fragment load is base + lane*16B: coalesced 1-KB wave reads
// from a 294-KB L2-resident table. No B LDS stage -> 32 KB LDS, 4 blocks/CU.
// ---------------------------------------------------------------------------

// ---------------------------------------------------------------------------
// Fused prologue: three independent producers in one launch, partitioned by
// blockIdx. edge blocks FIRST (latency-bound long pole) so cast_x/prep_w
// overlap underneath (verified r9 structure, 1 edge/thread).
// ---------------------------------------------------------------------------
__global__ __launch_bounds__(256) void fused_pre(
    const float* __restrict__ x, const float* __restrict__ W,
    const float* __restrict__ Wself,
    const int* __restrict__ src, const int* __restrict__ dst,
    unsigned short* __restrict__ xb, unsigned short* __restrict__ BT2,
    int* __restrict__ cnt, int* __restrict__ ebuf) {
    int b = blockIdx.x;
    int tid = threadIdx.x;
    if (b < EDGE_SECT) {
        // ---- edge_build: per-edge scatter into per-dst bucket ----
        int r = b / EB_BLOCKS, eb = b - r * EB_BLOCKS;
        int e = eb * 256 + tid;
        if (e < N_EDGES) {
            int s = src[r * N_EDGES + e];
            int d = dst[r * N_EDGES + e];
            int slot = atomicAdd(&cnt[d], 1);
            if (slot < CAP) ebuf[d * CAP + slot] = (r << 17) | s;
        }
    } else if (b < EDGE_SECT + CAST_BLOCKS) {
        // ---- cast_x: f32 -> bf16, 8 elems/thread, swizzled store ----
        int t = (b - EDGE_SECT) * 256 + tid;
        if (t < N_NODES * 16) {
            int row = t >> 4, g = t & 15;
            const float4* p = (const float4*)(x + (size_t)row * 128 + g * 8);
            float4 a = p[0], bb = p[1];
            unsigned short o[8] = { f2b(a.x), f2b(a.y), f2b(a.z), f2b(a.w),
                                    f2b(bb.x), f2b(bb.y), f2b(bb.z), f2b(bb.w) };
            int g2 = (g & 8) | ((g & 7) ^ (row & 7));
            *(int4*)(xb + (size_t)row * 128 + (g2 << 3)) = *(const int4*)o;
        }
    } else {
        // ---- prep_w: weight -> BT2 fragment-order bf16 ----
        int flat = (b - EDGE_SECT - CAST_BLOCKS) * 256 + tid;
        if (flat < 128 * KCOLS) {
            int n = flat / KCOLS, k = flat - n * KCOLS;
            float v;
            if (k < 1024) {
                int r = k >> 7, kk = k & 127;
                v = W[(r << 14) + (kk << 7) + n];
            } else {
                v = Wself[((k - 1024) << 7) + n];
            }
            int t2 = k >> 6, kb = (k >> 5) & 1, quad = (k >> 3) & 3, e = k & 7;
            int wc = n >> 6, j = (n >> 4) & 3, ml = n & 15;
            size_t idx = ((((((size_t)t2 * 2 + kb) * 2 + wc) * 4 + j) * 4 + quad)
                          << 7) + (ml << 3) + e;
            BT2[idx] = f2b(v);
        }
    }
}

// ---------------------------------------------------------------------------
// One wave per dst: Agg[d, r*128:+128] = inv_deg_r * sum_{edges r->d} xb[src]
// Relation-sorted flat walk, forced scalarization (readfirstlane on k,d ->
// all control flow is s_cmp/s_cbranch, readlane indices in SGPRs), 4-deep
// batched gather stream (verified r9 body).
// ---------------------------------------------------------------------------
__global__ __launch_bounds__(256) void agg_x(
    const unsigned short* __restrict__ xb, const int* __restrict__ ebuf,
    const int* __restrict__ cnt, unsigned short* __restrict__ Agg) {
    int d = (blockIdx.x << 2) + (threadIdx.x >> 6);
    if (d >= N_NODES) return;
    d = __builtin_amdgcn_readfirstlane(d);            // wave-uniform hint
    int lane = threadIdx.x & 63;

    int k = cnt[d]; if (k > CAP) k = CAP;
    k = __builtin_amdgcn_readfirstlane(k);            // wave-uniform hint
    int rec = (lane < k) ? ebuf[d * CAP + lane] : -1;
    int rl = rec >> 17;                    // -1 for idle lanes

    const unsigned int* xw = (const unsigned int*)xb;   // 2 bf16 per u32

    unsigned long long mask[8];
#pragma unroll
    for (int r = 0; r < 8; ++r) mask[r] = __ballot(rl == r);

    // ---- sort records by relation (stable in lane order) ----
    unsigned long long below = (lane == 63) ? 0x7FFFFFFFFFFFFFFFull
                                            : ((1ull << lane) - 1);
    int pre = 0;
    unsigned long long mymask = 0;
#pragma unroll
    for (int r = 0; r < 8; ++r) {
        pre += (rl > r) ? (int)__popcll(mask[r]) : 0;
        mymask = (rl == r) ? mask[r] : mymask;
    }
    int pos = (rl >= 0) ? (pre + (int)__popcll(mymask & below)) : lane;
    int srt = __builtin_amdgcn_ds_permute(pos << 2, rec);   // dst[pos] = rec

    int swu = lane ^ ((d & 7) << 2);                         // u32 col (swizzled)
    unsigned int* aggRow = (unsigned int*)(Agg + (size_t)d * 1024);

    auto store_r = [&](int rconst, float ax, float ay, int dg) {
        float inv = 1.0f / (float)(dg < 1 ? 1 : dg);
        unsigned int pk = (unsigned int)f2b(ax * inv)
                        | ((unsigned int)f2b(ay * inv) << 16);
        aggRow[(rconst << 6) + swu] = pk;
    };
    auto flush = [&](int r, float ax, float ay) {
        switch (r) {                     // scalar selector -> s_cbranch tree
            case 0: store_r(0, ax, ay, (int)__popcll(mask[0])); break;
            case 1: store_r(1, ax, ay, (int)__popcll(mask[1])); break;
            case 2: store_r(2, ax, ay, (int)__popcll(mask[2])); break;
            case 3: store_r(3, ax, ay, (int)__popcll(mask[3])); break;
            case 4: store_r(4, ax, ay, (int)__popcll(mask[4])); break;
            case 5: store_r(5, ax, ay, (int)__popcll(mask[5])); break;
            case 6: store_r(6, ax, ay, (int)__popcll(mask[6])); break;
            default: store_r(7, ax, ay, (int)__popcll(mask[7])); break;
        }
    };

    // ---- sorted walk: 4-deep batched loads, scalar boundary flush ----
    float axc = 0.f, ayc = 0.f;
    int cur = 0;
    if (k > 0) cur = __builtin_amdgcn_readlane(srt, 0) >> 17;

    for (int i = 0; i < k; i += 4) {
        int rc4[4];
#pragma unroll
        for (int j = 0; j < 4; ++j) {
            int ii = i + j; if (ii > k - 1) ii = k - 1;      // scalar clamp
            rc4[j] = __builtin_amdgcn_readlane(srt, ii);     // SGPR index
        }
        unsigned int y4[4];
#pragma unroll
        for (int j = 0; j < 4; ++j) {
            int s = rc4[j] & 0x1FFFF;                        // scalar
            y4[j] = xw[(size_t)s * 64 + (lane ^ ((s & 7) << 2))];
        }
#pragma unroll
        for (int j = 0; j < 4; ++j) {
            if (i + j < k) {                                  // scalar branch
                int rr = rc4[j] >> 17;                        // scalar
                if (rr != cur) {                              // scalar, rare
                    flush(cur, axc, ayc);
                    axc = 0.f; ayc = 0.f; cur = rr;
                }
                union { unsigned u; float f; } vx, vy;
                vx.u = y4[j] << 16;
                vy.u = y4[j] & 0xFFFF0000u;
                axc += vx.f;
                ayc += vy.f;
            }
        }
    }
    if (k > 0) flush(cur, axc, ayc);

    // zero-fill relations with no edges (mean = 0)
#pragma unroll
    for (int r = 0; r < 8; ++r)
        if (mask[r] == 0) aggRow[(r << 6) + swu] = 0u;
}

// ---------------------------------------------------------------------------
// out[N,128] f32 = relu( [Agg | xb][N,1152] @ BT^T + bias )
// 128x128 out tile/block, 4 waves 2x2. K-loop over 18 half-chunks of 64.
// A: double-buffered LDS via global_load_lds (XOR-swizzled read), 32 KB.
// B: fragment-order BT2 read straight from L2 — base + lane*16B, coalesced
//    1-KB wave loads, no LDS stage -> 4 blocks/CU (was 2).
// ---------------------------------------------------------------------------
__global__ __launch_bounds__(256, 4) void gemm_out(
    const unsigned short* __restrict__ Agg, const unsigned short* __restrict__ xb,
    const unsigned short* __restrict__ BT2, const float* __restrict__ bias,
    float* __restrict__ out) {
    __shared__ short As[2][128 * 64];
    int t = threadIdx.x;
    int rowBase = blockIdx.x * 128;

    int w = t >> 6, lane = t & 63;
    int wr = w >> 1, wc = w & 1;
    int ml = lane & 15, quad = lane >> 4;
    int sa = (lane & 7) << 4;          // read-side un-swizzle (row&7 == lane&7)

    int ri = lane >> 3;                // row within a 1 KB staging instruction
    int cb = (lane & 7) << 4;          // byte within 128-B row

    f32x4 acc[4][4];
#pragma unroll
    for (int i = 0; i < 4; ++i)
#pragma unroll
        for (int j = 0; j < 4; ++j)
            acc[i][j] = (f32x4){0.f, 0.f, 0.f, 0.f};

    auto stage = [&](int buf, int t2) {
        int kc = t2 >> 1, h = t2 & 1;
#pragma unroll
        for (int j = 0; j < 4; ++j) {
            int i = (w << 2) + j;                 // staging inst 0..15 (uniform)
            int row = (i << 3) + ri;              // LDS row 0..127
            int grow = rowBase + row;
            if (grow > N_NODES - 1) grow = N_NODES - 1;   // tail clamp
            const char* ga = (kc < 8)
                ? (const char*)Agg + (size_t)grow * 2048 + (kc << 8) + (h << 7) + cb
                : (const char*)xb  + (size_t)grow * 256  + (h << 7) + cb;
            gld16(ga, (char*)&As[buf][0] + (i << 10));    // uniform LDS base
        }
    };

    auto compute = [&](int buf, int t2) {
#pragma unroll
        for (int kb = 0; kb < 2; ++kb) {
            int off = ((kb << 6) + (quad << 4)) ^ sa;
            bf16x8 a[4], b[4];
#pragma unroll
            for (int i = 0; i < 4; ++i)
                a[i] = *(const bf16x8*)((const char*)&As[buf][0] +
                        (((wr << 6) + (i << 4) + ml) << 7) + off);
#pragma unroll
            for (int j = 0; j < 4; ++j) {
                size_t fb = (((((size_t)(t2 << 1) + kb) * 2 + wc) * 4 + j) << 9)
                          + ((size_t)lane << 3);
                b[j] = *(const bf16x8*)&BT2[fb];     // base + lane*16B, coalesced
            }
#pragma unroll
            for (int i = 0; i < 4; ++i)
#pragma unroll
                for (int j = 0; j < 4; ++j)
                    acc[i][j] = __builtin_amdgcn_mfma_f32_16x16x32_bf16(a[i], b[j], acc[i][j], 0, 0, 0);
        }
    };

    stage(0, 0);
    asm volatile("s_waitcnt vmcnt(0)" ::: "memory");
    __syncthreads();
    int cur = 0;
    for (int t2 = 0; t2 < 18; ++t2) {
        if (t2 + 1 < 18) stage(cur ^ 1, t2 + 1);   // prefetch next half-chunk
        compute(cur, t2);
        asm volatile("s_waitcnt vmcnt(0)" ::: "memory");
        __syncthreads();
        cur ^= 1;
    }

    // epilogue: + bias, relu, f32 store
#pragma unroll
    for (int i = 0; i < 4; ++i) {
#pragma unroll
        for (int j = 0; j < 4; ++j) {
            int col = wc * 64 + j * 16 + ml;
            float bv = bias[col];
#pragma unroll
            for (int rr = 0; rr < 4; ++rr) {
                int row = rowBase + wr * 64 + i * 16 + quad * 4 + rr;
                if (row < N_NODES) {
                    float v = acc[i][j][rr] + bv;
                    out[(size_t)row * 128 + col] = fmaxf(v, 0.f);
                }
            }
        }
    }
}

// ---------------------------------------------------------------------------
extern "C" void kernel_launch(void* const* d_in, const int* in_sizes, int n_in,
                              void* d_out, int out_size, void* d_ws, size_t ws_size,
                              hipStream_t stream) {
    const float* x     = (const float*)d_in[0];
    const float* W     = (const float*)d_in[1];
    const float* Wself = (const float*)d_in[2];
    const float* bias  = (const float*)d_in[3];
    const int*   src   = (const int*)d_in[4];
    const int*   dst   = (const int*)d_in[5];
    float* out = (float*)d_out;

    char* ws = (char*)d_ws;
    size_t off = 0;
    unsigned short* Agg = (unsigned short*)(ws + off); off += (size_t)N_NODES * 1024 * 2; // 204.8 MB
    unsigned short* xb  = (unsigned short*)(ws + off); off += (size_t)N_NODES * 128 * 2;  // 25.6 MB
    unsigned short* BT2 = (unsigned short*)(ws + off); off += (size_t)128 * KCOLS * 2;    // 0.3 MB
    int* cnt  = (int*)(ws + off); off += (size_t)N_NODES * 4;                             // 0.4 MB
    int* ebuf = (int*)(ws + off); off += (size_t)N_NODES * CAP * 4;                       // 25.6 MB

    hipMemsetAsync(cnt, 0, (size_t)N_NODES * 4, stream);

    fused_pre<<<TOTAL_PRE, 256, 0, stream>>>(x, W, Wself, src, dst,
                                             xb, BT2, cnt, ebuf);

    agg_x<<<(N_NODES + 3) / 4, 256, 0, stream>>>(xb, ebuf, cnt, Agg);

    gemm_out<<<(N_NODES + 127) / 128, 256, 0, stream>>>(Agg, xb, BT2, bias, out);
}